// Round 15
// baseline (465.408 us; speedup 1.0000x reference)
//
#include <hip/hip_runtime.h>
#include <math.h>

#define BB 4
#define SP 6272      // 28*28*8 spatial per batch
#define NSP 25088    // BB*SP
#define EPS 1e-5f

typedef unsigned short u16;
typedef __attribute__((ext_vector_type(8))) short v8s;   // 8 bf16 (4 VGPRs)
typedef __attribute__((ext_vector_type(4))) float v4f;   // MFMA accumulator

__device__ __forceinline__ u16 f2b(float f) {            // fp32 -> bf16 RNE
    unsigned u = __float_as_uint(f);
    return (u16)((u + 0x7fffu + ((u >> 16) & 1u)) >> 16);
}
__device__ __forceinline__ float b2f(u16 s) {
    return __uint_as_float(((unsigned)s) << 16);
}
__device__ __forceinline__ float b2f_lo(unsigned x) { return __uint_as_float(x << 16); }
__device__ __forceinline__ float b2f_hi(unsigned x) { return __uint_as_float(x & 0xffff0000u); }

// ---------------- conv1: 1->32, shuffle form (K=27 too small for MFMA) ----------------
__global__ __launch_bounds__(256) __attribute__((amdgpu_waves_per_eu(1, 4)))
void conv1_shfl(const float* __restrict__ X, const float* __restrict__ Wt,
                const float* __restrict__ bias, u16* __restrict__ Ybf)
{
    const int OT = 16;
    int xblk = blockIdx.x;                       // [0,104): 13 contiguous blocks per XCD
    int sblk = (xblk & 7) * 13 + (xblk >> 3);
    if (sblk >= 98) return;
    int s = sblk * 256 + threadIdx.x;
    int b = s / SP;
    int sp = s - b * SP;
    int d = sp / 224;
    int r = sp - d * 224;
    int h = r >> 3;
    int w = r & 7;
    int o0 = blockIdx.y * OT;

    float mdh[9]; int odh[9];
    #pragma unroll
    for (int i = 0; i < 3; i++) {
        int dd = d + i - 1;
        float md = ((unsigned)dd < 28u) ? 1.f : 0.f;
        int ddc = min(max(dd, 0), 27);
        #pragma unroll
        for (int j = 0; j < 3; j++) {
            int hh = h + j - 1;
            float mh = ((unsigned)hh < 28u) ? 1.f : 0.f;
            int hhc = min(max(hh, 0), 27);
            mdh[i * 3 + j] = md * mh;
            odh[i * 3 + j] = ddc * 224 + hhc * 8 + w;
        }
    }
    float mw0 = (w > 0) ? 1.f : 0.f;
    float mw2 = (w < 7) ? 1.f : 0.f;

    float acc[OT];
    #pragma unroll
    for (int oo = 0; oo < OT; oo++) acc[oo] = bias[o0 + oo];

    const float* xc = X + (size_t)b * SP;
    #pragma unroll
    for (int t9 = 0; t9 < 9; t9++) {
        float x0 = xc[odh[t9]];
        float m = mdh[t9];
        float xm = __shfl_up(x0, 1, 64) * (m * mw0);
        float xz = x0 * m;
        float xp = __shfl_down(x0, 1, 64) * (m * mw2);
        #pragma unroll
        for (int oo = 0; oo < OT; oo++) {
            const float* wp = Wt + (size_t)(o0 + oo) * 27 + t9 * 3;
            acc[oo] = fmaf(xm, wp[0], acc[oo]);
            acc[oo] = fmaf(xz, wp[1], acc[oo]);
            acc[oo] = fmaf(xp, wp[2], acc[oo]);
        }
    }
    unsigned pk[8];
    #pragma unroll
    for (int j = 0; j < 8; j++) {
        float v0 = fmaxf(acc[2 * j], 0.f);
        float v1 = fmaxf(acc[2 * j + 1], 0.f);
        pk[j] = (unsigned)f2b(v0) | ((unsigned)f2b(v1) << 16);
    }
    u16* row = Ybf + (size_t)(b * SP + sp) * 32 + o0;
    *(uint4*)(row)     = make_uint4(pk[0], pk[1], pk[2], pk[3]);
    *(uint4*)(row + 8) = make_uint4(pk[4], pk[5], pk[6], pk[7]);
}

// ---------------- stats over y1bf (channel-minor bf16, C=32) ----------------
__global__ __launch_bounds__(256) void stats32(const u16* __restrict__ Y,
        float* __restrict__ s_sum, float* __restrict__ s_sq)
{
    __shared__ float ls[32], lq[32];
    int t = threadIdx.x;
    if (t < 32) { ls[t] = 0.f; lq[t] = 0.f; }
    __syncthreads();
    int co = t & 3, pl = t >> 2;
    int base = blockIdx.x * 256;
    float rs[8] = {0,0,0,0,0,0,0,0}, rq[8] = {0,0,0,0,0,0,0,0};
    #pragma unroll
    for (int i = 0; i < 4; i++) {
        int pos = base + i * 64 + pl;
        uint4 v = *(const uint4*)(Y + (size_t)pos * 32 + co * 8);
        float f0 = b2f_lo(v.x), f1 = b2f_hi(v.x);
        float f2 = b2f_lo(v.y), f3 = b2f_hi(v.y);
        float f4 = b2f_lo(v.z), f5 = b2f_hi(v.z);
        float f6 = b2f_lo(v.w), f7 = b2f_hi(v.w);
        rs[0] += f0; rq[0] += f0 * f0;  rs[1] += f1; rq[1] += f1 * f1;
        rs[2] += f2; rq[2] += f2 * f2;  rs[3] += f3; rq[3] += f3 * f3;
        rs[4] += f4; rq[4] += f4 * f4;  rs[5] += f5; rq[5] += f5 * f5;
        rs[6] += f6; rq[6] += f6 * f6;  rs[7] += f7; rq[7] += f7 * f7;
    }
    #pragma unroll
    for (int j = 0; j < 8; j++) {
        atomicAdd(&ls[co * 8 + j], rs[j]);
        atomicAdd(&lq[co * 8 + j], rq[j]);
    }
    __syncthreads();
    if (t < 32) {
        atomicAdd(&s_sum[t], ls[t]);
        atomicAdd(&s_sq[t], lq[t]);
    }
}

// ---------------- merged weight prepack (block-aligned ranges -> uniform branch) ----
__global__ __launch_bounds__(256) void prepack_all(const float* __restrict__ c2w,
        const float* __restrict__ c3w, const float* __restrict__ ow,
        const float* __restrict__ dw, u16* __restrict__ wpk2,
        u16* __restrict__ wpk3, u16* __restrict__ wpko, u16* __restrict__ dwa)
{
    int idx = blockIdx.x * 256 + threadIdx.x;
    if (idx < 55296) {
        int t = idx / 2048, rem = idx & 2047, o = rem >> 5, c = rem & 31;
        wpk2[idx] = f2b(c2w[((size_t)o * 32 + c) * 27 + t]);
    } else if (idx < 276480) {
        int i = idx - 55296;
        int t = i / 8192, rem = i & 8191, o = rem >> 6, c = rem & 63;
        wpk3[i] = f2b(c3w[((size_t)o * 64 + c) * 27 + t]);
    } else if (idx < 718848) {
        int i = idx - 276480;
        int t = i / 16384, rem = i & 16383, o = rem >> 7, c = rem & 127;
        wpko[i] = f2b((o < 81) ? ow[((size_t)o * 128 + c) * 27 + t] : 0.f);
    } else {
        int i = idx - 718848;   // dwa[n][ot][kc][q][r][j]
        int j = i & 7, r = (i >> 3) & 15, q = (i >> 7) & 3;
        int kc = (i >> 9) & 3, ot = (i >> 11) & 7, n = i >> 14;
        int o = ot * 16 + r, c = kc * 32 + q * 8 + j;
        dwa[i] = f2b(dw[((size_t)o * 128 + c) * 27 + n]);
    }
}

// ---------------- MFMA implicit-GEMM conv 3x3x3 (CIN>=32, bf16) ----------------
// BNIN: apply per-channel affine (from stats) during LDS staging.
// NO: o-tiles per wave (wave computes o and o+64) -- doubles MFMA per A-ds_read
// (ds:MFMA 1:1 -> 1:2) and halves block count / staging traffic.
template<int CIN, int OPAD, bool OFFOUT, bool BNIN, int NO>
__global__ __launch_bounds__(256) __attribute__((amdgpu_waves_per_eu(1, 4)))
void conv_mfma(const u16* __restrict__ X, const u16* __restrict__ Wpk,
               const float* __restrict__ bias, u16* __restrict__ Ybf,
               float* __restrict__ offs, float* __restrict__ s_sum,
               float* __restrict__ s_sq, const float* __restrict__ in_sum,
               const float* __restrict__ in_sq, const float* __restrict__ in_g,
               const float* __restrict__ in_b)
{
    const int HS = CIN + 8;                 // LDS stride per position (bf16 units)
    __shared__ u16 xs[160 * HS];            // [dz 0..3][hz 0..3][wz 0..9][c]
    __shared__ float scin[BNIN ? CIN : 1], shin[BNIN ? CIN : 1];

    int tid = threadIdx.x;
    int fid = blockIdx.x;                   // [0,784) = 8 XCDs x 98
    int g = (fid & 7) * 98 + (fid >> 3);
    int b = g / 196;
    int rem = g - b * 196;
    int d0 = (rem / 14) * 2, h0 = (rem % 14) * 2;

    if (BNIN) {
        if (tid < CIN) {
            float m = in_sum[tid] * (1.f / NSP);
            float v = in_sq[tid] * (1.f / NSP) - m * m;
            float sc = in_g[tid] * rsqrtf(v + EPS);
            scin[tid] = sc;
            shin[tid] = in_b[tid] - m * sc;
        }
        __syncthreads();
    }

    const int NCH = CIN / 8;
    for (int idx = tid; idx < 160 * NCH; idx += 256) {
        int pos = idx / NCH, ch = idx - pos * NCH;
        int dz = pos / 40, r2 = pos - dz * 40;
        int hz = r2 / 10, wz = r2 - hz * 10;
        int dd = d0 + dz - 1, hh = h0 + hz - 1, ww = wz - 1;
        uint4 val = make_uint4(0, 0, 0, 0);
        if ((unsigned)dd < 28u && (unsigned)hh < 28u && (unsigned)ww < 8u) {
            val = *(const uint4*)(X + ((size_t)(b * SP + dd * 224 + hh * 8 + ww) * CIN + ch * 8));
            if (BNIN) {
                int cb = ch * 8;
                float f0 = b2f_lo(val.x) * scin[cb]     + shin[cb];
                float f1 = b2f_hi(val.x) * scin[cb + 1] + shin[cb + 1];
                float f2 = b2f_lo(val.y) * scin[cb + 2] + shin[cb + 2];
                float f3 = b2f_hi(val.y) * scin[cb + 3] + shin[cb + 3];
                float f4 = b2f_lo(val.z) * scin[cb + 4] + shin[cb + 4];
                float f5 = b2f_hi(val.z) * scin[cb + 5] + shin[cb + 5];
                float f6 = b2f_lo(val.w) * scin[cb + 6] + shin[cb + 6];
                float f7 = b2f_hi(val.w) * scin[cb + 7] + shin[cb + 7];
                val.x = (unsigned)f2b(f0) | ((unsigned)f2b(f1) << 16);
                val.y = (unsigned)f2b(f2) | ((unsigned)f2b(f3) << 16);
                val.z = (unsigned)f2b(f4) | ((unsigned)f2b(f5) << 16);
                val.w = (unsigned)f2b(f6) | ((unsigned)f2b(f7) << 16);
            }
        }
        *(uint4*)(xs + pos * HS + ch * 8) = val;
    }
    __syncthreads();

    int l = tid & 63, wv = tid >> 6;
    int q = l >> 4, r = l & 15;
    int hl = r >> 3, wl = r & 7;
    int o_base = blockIdx.y * 64 * NO + wv * 16;

    const u16* a0p = xs + ((4 + hl + 1) * 10 + wl + 1) * HS + 8 * q;  // dl=0
    const u16* a1p = a0p + 40 * HS;                                   // dl=1
    const u16* wp[NO];
    #pragma unroll
    for (int oti = 0; oti < NO; oti++)
        wp[oti] = Wpk + (size_t)(o_base + oti * 64 + r) * CIN + 8 * q;

    v4f acc[NO][2];
    #pragma unroll
    for (int oti = 0; oti < NO; oti++) {
        acc[oti][0] = (v4f){0.f, 0.f, 0.f, 0.f};
        acc[oti][1] = (v4f){0.f, 0.f, 0.f, 0.f};
    }
    #pragma unroll
    for (int t = 0; t < 27; t++) {
        const int koff = ((t / 9) - 1) * 40 + (((t / 3) % 3) - 1) * 10 + (t % 3) - 1;
        #pragma unroll
        for (int c0 = 0; c0 < CIN; c0 += 32) {
            v8s a0 = *(const v8s*)(a0p + koff * HS + c0);
            v8s a1 = *(const v8s*)(a1p + koff * HS + c0);
            #pragma unroll
            for (int oti = 0; oti < NO; oti++) {
                v8s bf = *(const v8s*)(wp[oti] + (size_t)t * OPAD * CIN + c0);
                acc[oti][0] = __builtin_amdgcn_mfma_f32_16x16x32_bf16(a0, bf, acc[oti][0], 0, 0, 0);
                acc[oti][1] = __builtin_amdgcn_mfma_f32_16x16x32_bf16(a1, bf, acc[oti][1], 0, 0, 0);
            }
        }
    }

    #pragma unroll
    for (int oti = 0; oti < NO; oti++) {
        int o = o_base + oti * 64 + r;
        if (OFFOUT) {
            float bo = (o < 81) ? bias[o] : 0.f;
            #pragma unroll
            for (int s2 = 0; s2 < 2; s2++) {
                v4f A = acc[oti][s2];
                #pragma unroll
                for (int rg = 0; rg < 4; rg++) {
                    int rowl = q * 4 + rg;
                    int sp = (d0 + s2) * 224 + (h0 + (rowl >> 3)) * 8 + (rowl & 7);
                    if (o < 81) offs[((size_t)(b * 81 + o)) * SP + sp] = A[rg] + bo;
                }
            }
        } else {
            float bo = bias[o];
            float rs = 0.f, rq = 0.f;
            #pragma unroll
            for (int s2 = 0; s2 < 2; s2++) {
                v4f A = acc[oti][s2];
                #pragma unroll
                for (int rg = 0; rg < 4; rg++) {
                    int rowl = q * 4 + rg;
                    int sp = (d0 + s2) * 224 + (h0 + (rowl >> 3)) * 8 + (rowl & 7);
                    float v = fmaxf(A[rg] + bo, 0.f);
                    Ybf[(size_t)(b * SP + sp) * OPAD + o] = f2b(v);
                    rs += v; rq += v * v;
                }
            }
            rs += __shfl_xor(rs, 16, 64); rs += __shfl_xor(rs, 32, 64);
            rq += __shfl_xor(rq, 16, 64); rq += __shfl_xor(rq, 32, 64);
            if (l < 16) {
                atomicAdd(&s_sum[o_base + oti * 64 + l], rs);
                atomicAdd(&s_sq[o_base + oti * 64 + l], rq);
            }
        }
    }
}

// ---------------- deformable conv (MFMA) -- R12 structure + fused BN3 ----------------
// R12's 3-barrier / 32-pos loop is the measured local optimum (R11/R13/R14 all
// regressed). Only change: input is PRE-BN y3bf; BN fused into the sample via
// va_c = sc_c * sum(g*y_c) + sh_c * sum(g)   (pad corners have g=0 -> exact).
// This kills the bn_bf<128> pass and the x3bf buffer.
__global__ __launch_bounds__(256) __attribute__((amdgpu_waves_per_eu(1, 4)))
void deform_pool(const u16* __restrict__ Ht, const float* __restrict__ OFF,
                 const u16* __restrict__ Wa, const float* __restrict__ db,
                 float* __restrict__ pooledraw, float* __restrict__ sumsq4,
                 const float* __restrict__ s3sum, const float* __restrict__ s3sq,
                 const float* __restrict__ g3, const float* __restrict__ b3)
{
    __shared__ float offs_lds[81 * 32];     // [ch][p]
    __shared__ float scf[128], shf[128];
    __shared__ int ig_s[32][8][2];          // [p][corner][{idx, g bits}]
    __shared__ u16 Vb[32][136];             // B operand [p][c] bf16, row pad +8
    __shared__ float reds[128], redq[128];

    int fid = blockIdx.x;          // [0,800)
    int xcd = fid & 7;
    int local = fid >> 3;          // [0,100)
    if (local >= 98) return;
    int b = xcd >> 1;
    int d = (xcd & 1) * 14 + local / 7;
    int h0 = (local % 7) * 4;

    int t = threadIdx.x;
    if (t < 128) {
        reds[t] = 0.f; redq[t] = 0.f;
        float m = s3sum[t] * (1.f / NSP);
        float v = s3sq[t] * (1.f / NSP) - m * m;
        float sc = g3[t] * rsqrtf(v + EPS);
        scf[t] = sc;
        shf[t] = b3[t] - m * sc;
    }

    int gp = t >> 3, gcr = t & 7;                  // geometry role
    int glh = gp >> 3, gw = gp & 7, gh = h0 + glh;
    int co = t & 15, pg = t >> 4;                  // phase2 role: c-oct, p-pair
    int l = t & 63, wv = t >> 6;                   // phase3 role
    int q = l >> 4, r = l & 15;

    v4f acc[2][2];                                 // [o-tile][p-tile]
    acc[0][0] = (v4f){0.f,0.f,0.f,0.f}; acc[0][1] = (v4f){0.f,0.f,0.f,0.f};
    acc[1][0] = (v4f){0.f,0.f,0.f,0.f}; acc[1][1] = (v4f){0.f,0.f,0.f,0.f};

    const u16* hb = Ht + (size_t)b * SP * 128;

    // ---- stage offsets for this block's 32 positions (coalesced, once) ----
    for (int i = t; i < 2592; i += 256) {
        int ch = i >> 5, p = i & 31;
        offs_lds[i] = OFF[(size_t)b * 81 * SP + (size_t)ch * SP
                          + d * 224 + (h0 + (p >> 3)) * 8 + (p & 7)];
    }
    __syncthreads();

    // BN affine for this thread's 8 channels (phase2 role), held in registers
    float scr[8], shr[8];
    #pragma unroll
    for (int i = 0; i < 8; i++) { scr[i] = scf[co * 8 + i]; shr[i] = shf[co * 8 + i]; }

    for (int n = 0; n < 27; n++) {
        __syncthreads();   // prev phase3 done reading Vb
        {   // ---- geometry for (n, gp, gcr) ----
            int kd = n / 9 - 1, kh = (n / 3) % 3 - 1, kw = n % 3 - 1;
            float od  = offs_lds[n * 32 + gp];
            float oh  = offs_lds[(27 + n) * 32 + gp];
            float owv = offs_lds[(54 + n) * 32 + gp];
            float pd = fminf(fmaxf((float)(d + 1 + kd) + od, 0.f), 29.f);
            float ph = fminf(fmaxf((float)(gh + 1 + kh) + oh, 0.f), 29.f);
            float pw = fminf(fmaxf((float)(gw + 1 + kw) + owv, 0.f), 9.f);
            float qd = fminf(floorf(pd), 28.f);
            float qh = fminf(floorf(ph), 28.f);
            float qw = fminf(floorf(pw), 8.f);
            float td = fminf(pd - qd, 1.f);
            float th = fminf(ph - qh, 1.f);
            float tw = fminf(pw - qw, 1.f);
            int iqd = (int)qd - 1, iqh = (int)qh - 1, iqw = (int)qw - 1;
            int i = gcr >> 2, j = (gcr >> 1) & 1, k = gcr & 1;
            int du = iqd + i, hu = iqh + j, wu = iqw + k;
            bool val = (unsigned)du < 28u && (unsigned)hu < 28u && (unsigned)wu < 8u;
            float gg = (i ? td : 1.f - td) * (j ? th : 1.f - th) * (k ? tw : 1.f - tw);
            ig_s[gp][gcr][0] = val ? (du * 224 + hu * 8 + wu) : 0;
            ig_s[gp][gcr][1] = __float_as_int(val ? gg : 0.f);
        }
        __syncthreads();
        // ---- phase 2: V[p][c] = BN-fused trilinear sample, 8 channels/load ----
        #pragma unroll
        for (int pp = 0; pp < 2; pp++) {
            int p = pg * 2 + pp;
            float ya[8] = {0.f,0.f,0.f,0.f,0.f,0.f,0.f,0.f};
            float sg = 0.f;
            #pragma unroll
            for (int cr = 0; cr < 8; cr++) {
                int2 pr = *(const int2*)&ig_s[p][cr][0];
                float gg = __int_as_float(pr.y);
                uint4 xv = *(const uint4*)(hb + (size_t)pr.x * 128 + co * 8);
                sg += gg;
                ya[0] = fmaf(gg, b2f_lo(xv.x), ya[0]);
                ya[1] = fmaf(gg, b2f_hi(xv.x), ya[1]);
                ya[2] = fmaf(gg, b2f_lo(xv.y), ya[2]);
                ya[3] = fmaf(gg, b2f_hi(xv.y), ya[3]);
                ya[4] = fmaf(gg, b2f_lo(xv.z), ya[4]);
                ya[5] = fmaf(gg, b2f_hi(xv.z), ya[5]);
                ya[6] = fmaf(gg, b2f_lo(xv.w), ya[6]);
                ya[7] = fmaf(gg, b2f_hi(xv.w), ya[7]);
            }
            float va[8];
            #pragma unroll
            for (int i = 0; i < 8; i++) va[i] = fmaf(scr[i], ya[i], shr[i] * sg);
            uint4 pk;
            pk.x = (unsigned)f2b(va[0]) | ((unsigned)f2b(va[1]) << 16);
            pk.y = (unsigned)f2b(va[2]) | ((unsigned)f2b(va[3]) << 16);
            pk.z = (unsigned)f2b(va[4]) | ((unsigned)f2b(va[5]) << 16);
            pk.w = (unsigned)f2b(va[6]) | ((unsigned)f2b(va[7]) << 16);
            *(uint4*)&Vb[p][co * 8] = pk;
        }
        __syncthreads();
        // ---- phase 3: out[o][p] += W[o][c] * V[c][p] via MFMA ----
        const u16* wn = Wa + (size_t)n * 16384;
        #pragma unroll
        for (int oti = 0; oti < 2; oti++) {
            int ot = wv * 2 + oti;
            #pragma unroll
            for (int kc = 0; kc < 4; kc++) {
                v8s af = *(const v8s*)(wn + ((((ot * 4 + kc) * 4 + q) * 16 + r) * 8));
                v8s bf0 = *(const v8s*)&Vb[r][kc * 32 + q * 8];
                v8s bf1 = *(const v8s*)&Vb[16 + r][kc * 32 + q * 8];
                acc[oti][0] = __builtin_amdgcn_mfma_f32_16x16x32_bf16(af, bf0, acc[oti][0], 0, 0, 0);
                acc[oti][1] = __builtin_amdgcn_mfma_f32_16x16x32_bf16(af, bf1, acc[oti][1], 0, 0, 0);
            }
        }
    }

    // ---- epilogue: bias + relu + pooled sum / sumsq ----
    #pragma unroll
    for (int oti = 0; oti < 2; oti++) {
        #pragma unroll
        for (int rg = 0; rg < 4; rg++) {
            int o = (wv * 2 + oti) * 16 + q * 4 + rg;
            float bo = db[o];
            float v0 = fmaxf(acc[oti][0][rg] + bo, 0.f);
            float v1 = fmaxf(acc[oti][1][rg] + bo, 0.f);
            float s = v0 + v1, qq = v0 * v0 + v1 * v1;
            s += __shfl_xor(s, 1, 64);  qq += __shfl_xor(qq, 1, 64);
            s += __shfl_xor(s, 2, 64);  qq += __shfl_xor(qq, 2, 64);
            s += __shfl_xor(s, 4, 64);  qq += __shfl_xor(qq, 4, 64);
            s += __shfl_xor(s, 8, 64);  qq += __shfl_xor(qq, 8, 64);
            if (r == 0) { atomicAdd(&reds[o], s); atomicAdd(&redq[o], qq); }
        }
    }
    __syncthreads();
    if (t < 128) {
        atomicAdd(&pooledraw[b * 128 + t], reds[t]);
        atomicAdd(&sumsq4[t], redq[t]);
    }
}

// ---------------- tail kernel: block 0 = BN4+pool+FC+log_softmax; rest publish offsets ----
__global__ __launch_bounds__(256) void final_head_emit(const float* __restrict__ pooledraw,
        const float* __restrict__ sumsq4, const float* __restrict__ g4,
        const float* __restrict__ b4, const float* __restrict__ fcw,
        const float* __restrict__ fcb, const float* __restrict__ offw,
        float* __restrict__ out)
{
    int t = threadIdx.x;
    if (blockIdx.x > 0) {   // offsets copy: 1985 blocks x 256 x float4
        int idx = (blockIdx.x - 1) * 256 + t;
        if (idx < 508032) {
            float4 v = ((const float4*)offw)[idx];
            ((float4*)(out + 40))[idx] = v;
        }
        return;
    }
    __shared__ float pooled_s[4][128];
    __shared__ float logits[4][10];
    if (t < 128) {
        float s0 = pooledraw[t], s1 = pooledraw[128 + t];
        float s2 = pooledraw[256 + t], s3 = pooledraw[384 + t];
        float tot = s0 + s1 + s2 + s3;
        float m  = tot * (1.f / NSP);
        float v  = sumsq4[t] * (1.f / NSP) - m * m;
        float sc = g4[t] * rsqrtf(v + EPS);
        float sh = b4[t] - m * sc;
        pooled_s[0][t] = s0 * (1.f / SP) * sc + sh;
        pooled_s[1][t] = s1 * (1.f / SP) * sc + sh;
        pooled_s[2][t] = s2 * (1.f / SP) * sc + sh;
        pooled_s[3][t] = s3 * (1.f / SP) * sc + sh;
    }
    __syncthreads();
    if (t < 40) {
        int b = t / 10, j = t % 10;
        float l = fcb[j];
        for (int c = 0; c < 128; c++) l = fmaf(pooled_s[b][c], fcw[j * 128 + c], l);
        logits[b][j] = l;
    }
    __syncthreads();
    if (t < 4) {
        float mx = -1e30f;
        for (int j = 0; j < 10; j++) mx = fmaxf(mx, logits[t][j]);
        float se = 0.f;
        for (int j = 0; j < 10; j++) se += expf(logits[t][j] - mx);
        float lse = mx + logf(se);
        for (int j = 0; j < 10; j++) out[t * 10 + j] = logits[t][j] - lse;
    }
}

extern "C" void kernel_launch(void* const* d_in, const int* in_sizes, int n_in,
                              void* d_out, int out_size, void* d_ws, size_t ws_size,
                              hipStream_t stream)
{
    (void)in_sizes; (void)n_in; (void)out_size; (void)ws_size;
    const float* x   = (const float*)d_in[0];
    const float* c1w = (const float*)d_in[1];
    const float* c1b = (const float*)d_in[2];
    const float* g1  = (const float*)d_in[3];
    const float* b1  = (const float*)d_in[4];
    const float* c2w = (const float*)d_in[5];
    const float* c2b = (const float*)d_in[6];
    const float* g2  = (const float*)d_in[7];
    const float* b2  = (const float*)d_in[8];
    const float* c3w = (const float*)d_in[9];
    const float* c3b = (const float*)d_in[10];
    const float* g3  = (const float*)d_in[11];
    const float* b3  = (const float*)d_in[12];
    const float* ow  = (const float*)d_in[13];
    const float* ob  = (const float*)d_in[14];
    const float* dw  = (const float*)d_in[15];
    const float* db  = (const float*)d_in[16];
    const float* g4  = (const float*)d_in[17];
    const float* b4  = (const float*)d_in[18];
    const float* fcw = (const float*)d_in[19];
    const float* fcb = (const float*)d_in[20];

    float* ws = (float*)d_ws;
    float* S1 = ws + 0,   *Q1 = ws + 32;
    float* S2 = ws + 64,  *Q2 = ws + 128;
    float* S3 = ws + 192, *Q3 = ws + 320;
    float* PO = ws + 448;   // 4*128
    float* Q4 = ws + 960;   // 128
    u16* y1bf = (u16*)(ws + 2048);         // NSP*32
    u16* y2bf = y1bf + 802816;             // NSP*64
    u16* y3bf = y2bf + 1605632;            // NSP*128
    u16* wpk2 = y3bf + 3211264;            // 27*64*32
    u16* wpk3 = wpk2 + 55296;              // 27*128*64
    u16* wpko = wpk3 + 221184;             // 27*128*128 (o>=81 zero)
    u16* dwa  = wpko + 442368;             // 27*128*128 A-frag layout bf16
    float* offw = (float*)(dwa + 442368);  // 4*81*SP fp32 (ws copy of offsets)

    float* outf = (float*)d_out;

    hipMemsetAsync(ws, 0, 2048 * sizeof(float), stream);
    prepack_all<<<4536, 256, 0, stream>>>(c2w, c3w, ow, dw, wpk2, wpk3, wpko, dwa);

    conv1_shfl<<<dim3(104, 2), 256, 0, stream>>>(x, c1w, c1b, y1bf);
    stats32<<<98, 256, 0, stream>>>(y1bf, S1, Q1);

    conv_mfma<32, 64, false, true, 1><<<dim3(784, 1), 256, 0, stream>>>(
        y1bf, wpk2, c2b, y2bf, nullptr, S2, Q2, S1, Q1, g1, b1);

    conv_mfma<64, 128, false, true, 2><<<dim3(784, 1), 256, 0, stream>>>(
        y2bf, wpk3, c3b, y3bf, nullptr, S3, Q3, S2, Q2, g2, b2);

    // offsets computed into WORKSPACE; d_out is written only at the tail
    conv_mfma<128, 128, true, true, 2><<<dim3(784, 1), 256, 0, stream>>>(
        y3bf, wpko, ob, nullptr, offw, nullptr, nullptr, S3, Q3, g3, b3);
    deform_pool<<<800, 256, 0, stream>>>(y3bf, offw, dwa, db, PO, Q4, S3, Q3, g3, b3);
    final_head_emit<<<1986, 256, 0, stream>>>(PO, Q4, g4, b4, fcw, fcb, offw, outf);
}

// Round 16
// 428.595 us; speedup vs baseline: 1.0859x; 1.0859x over previous
//
#include <hip/hip_runtime.h>
#include <math.h>

#define BB 4
#define SP 6272      // 28*28*8 spatial per batch
#define NSP 25088    // BB*SP
#define EPS 1e-5f

typedef unsigned short u16;
typedef __attribute__((ext_vector_type(8))) short v8s;   // 8 bf16 (4 VGPRs)
typedef __attribute__((ext_vector_type(4))) float v4f;   // MFMA accumulator

__device__ __forceinline__ u16 f2b(float f) {            // fp32 -> bf16 RNE
    unsigned u = __float_as_uint(f);
    return (u16)((u + 0x7fffu + ((u >> 16) & 1u)) >> 16);
}
__device__ __forceinline__ float b2f(u16 s) {
    return __uint_as_float(((unsigned)s) << 16);
}
__device__ __forceinline__ float b2f_lo(unsigned x) { return __uint_as_float(x << 16); }
__device__ __forceinline__ float b2f_hi(unsigned x) { return __uint_as_float(x & 0xffff0000u); }

// ---------------- conv1: 1->32, shuffle form (K=27 too small for MFMA) ----------------
__global__ __launch_bounds__(256) __attribute__((amdgpu_waves_per_eu(1, 4)))
void conv1_shfl(const float* __restrict__ X, const float* __restrict__ Wt,
                const float* __restrict__ bias, u16* __restrict__ Ybf)
{
    const int OT = 16;
    int xblk = blockIdx.x;                       // [0,104): 13 contiguous blocks per XCD
    int sblk = (xblk & 7) * 13 + (xblk >> 3);
    if (sblk >= 98) return;
    int s = sblk * 256 + threadIdx.x;
    int b = s / SP;
    int sp = s - b * SP;
    int d = sp / 224;
    int r = sp - d * 224;
    int h = r >> 3;
    int w = r & 7;
    int o0 = blockIdx.y * OT;

    float mdh[9]; int odh[9];
    #pragma unroll
    for (int i = 0; i < 3; i++) {
        int dd = d + i - 1;
        float md = ((unsigned)dd < 28u) ? 1.f : 0.f;
        int ddc = min(max(dd, 0), 27);
        #pragma unroll
        for (int j = 0; j < 3; j++) {
            int hh = h + j - 1;
            float mh = ((unsigned)hh < 28u) ? 1.f : 0.f;
            int hhc = min(max(hh, 0), 27);
            mdh[i * 3 + j] = md * mh;
            odh[i * 3 + j] = ddc * 224 + hhc * 8 + w;
        }
    }
    float mw0 = (w > 0) ? 1.f : 0.f;
    float mw2 = (w < 7) ? 1.f : 0.f;

    float acc[OT];
    #pragma unroll
    for (int oo = 0; oo < OT; oo++) acc[oo] = bias[o0 + oo];

    const float* xc = X + (size_t)b * SP;
    #pragma unroll
    for (int t9 = 0; t9 < 9; t9++) {
        float x0 = xc[odh[t9]];
        float m = mdh[t9];
        float xm = __shfl_up(x0, 1, 64) * (m * mw0);
        float xz = x0 * m;
        float xp = __shfl_down(x0, 1, 64) * (m * mw2);
        #pragma unroll
        for (int oo = 0; oo < OT; oo++) {
            const float* wp = Wt + (size_t)(o0 + oo) * 27 + t9 * 3;
            acc[oo] = fmaf(xm, wp[0], acc[oo]);
            acc[oo] = fmaf(xz, wp[1], acc[oo]);
            acc[oo] = fmaf(xp, wp[2], acc[oo]);
        }
    }
    unsigned pk[8];
    #pragma unroll
    for (int j = 0; j < 8; j++) {
        float v0 = fmaxf(acc[2 * j], 0.f);
        float v1 = fmaxf(acc[2 * j + 1], 0.f);
        pk[j] = (unsigned)f2b(v0) | ((unsigned)f2b(v1) << 16);
    }
    u16* row = Ybf + (size_t)(b * SP + sp) * 32 + o0;
    *(uint4*)(row)     = make_uint4(pk[0], pk[1], pk[2], pk[3]);
    *(uint4*)(row + 8) = make_uint4(pk[4], pk[5], pk[6], pk[7]);
}

// ---------------- stats over y1bf (channel-minor bf16, C=32) ----------------
__global__ __launch_bounds__(256) void stats32(const u16* __restrict__ Y,
        float* __restrict__ s_sum, float* __restrict__ s_sq)
{
    __shared__ float ls[32], lq[32];
    int t = threadIdx.x;
    if (t < 32) { ls[t] = 0.f; lq[t] = 0.f; }
    __syncthreads();
    int co = t & 3, pl = t >> 2;
    int base = blockIdx.x * 256;
    float rs[8] = {0,0,0,0,0,0,0,0}, rq[8] = {0,0,0,0,0,0,0,0};
    #pragma unroll
    for (int i = 0; i < 4; i++) {
        int pos = base + i * 64 + pl;
        uint4 v = *(const uint4*)(Y + (size_t)pos * 32 + co * 8);
        float f0 = b2f_lo(v.x), f1 = b2f_hi(v.x);
        float f2 = b2f_lo(v.y), f3 = b2f_hi(v.y);
        float f4 = b2f_lo(v.z), f5 = b2f_hi(v.z);
        float f6 = b2f_lo(v.w), f7 = b2f_hi(v.w);
        rs[0] += f0; rq[0] += f0 * f0;  rs[1] += f1; rq[1] += f1 * f1;
        rs[2] += f2; rq[2] += f2 * f2;  rs[3] += f3; rq[3] += f3 * f3;
        rs[4] += f4; rq[4] += f4 * f4;  rs[5] += f5; rq[5] += f5 * f5;
        rs[6] += f6; rq[6] += f6 * f6;  rs[7] += f7; rq[7] += f7 * f7;
    }
    #pragma unroll
    for (int j = 0; j < 8; j++) {
        atomicAdd(&ls[co * 8 + j], rs[j]);
        atomicAdd(&lq[co * 8 + j], rq[j]);
    }
    __syncthreads();
    if (t < 32) {
        atomicAdd(&s_sum[t], ls[t]);
        atomicAdd(&s_sq[t], lq[t]);
    }
}

// ---------------- merged weight prepack (block-aligned ranges -> uniform branch) ----
__global__ __launch_bounds__(256) void prepack_all(const float* __restrict__ c2w,
        const float* __restrict__ c3w, const float* __restrict__ ow,
        const float* __restrict__ dw, u16* __restrict__ wpk2,
        u16* __restrict__ wpk3, u16* __restrict__ wpko, u16* __restrict__ dwa)
{
    int idx = blockIdx.x * 256 + threadIdx.x;
    if (idx < 55296) {
        int t = idx / 2048, rem = idx & 2047, o = rem >> 5, c = rem & 31;
        wpk2[idx] = f2b(c2w[((size_t)o * 32 + c) * 27 + t]);
    } else if (idx < 276480) {
        int i = idx - 55296;
        int t = i / 8192, rem = i & 8191, o = rem >> 6, c = rem & 63;
        wpk3[i] = f2b(c3w[((size_t)o * 64 + c) * 27 + t]);
    } else if (idx < 718848) {
        int i = idx - 276480;
        int t = i / 16384, rem = i & 16383, o = rem >> 7, c = rem & 127;
        wpko[i] = f2b((o < 81) ? ow[((size_t)o * 128 + c) * 27 + t] : 0.f);
    } else {
        int i = idx - 718848;   // dwa[n][ot][kc][q][r][j]
        int j = i & 7, r = (i >> 3) & 15, q = (i >> 7) & 3;
        int kc = (i >> 9) & 3, ot = (i >> 11) & 7, n = i >> 14;
        int o = ot * 16 + r, c = kc * 32 + q * 8 + j;
        dwa[i] = f2b(dw[((size_t)o * 128 + c) * 27 + n]);
    }
}

// ---------------- MFMA implicit-GEMM conv 3x3x3 (CIN>=32, bf16) ----------------
// BNIN: apply per-channel affine (from stats) during LDS staging.
template<int CIN, int OPAD, bool OFFOUT, bool BNIN>
__global__ __launch_bounds__(256) __attribute__((amdgpu_waves_per_eu(1, 4)))
void conv_mfma(const u16* __restrict__ X, const u16* __restrict__ Wpk,
               const float* __restrict__ bias, u16* __restrict__ Ybf,
               float* __restrict__ offs, float* __restrict__ s_sum,
               float* __restrict__ s_sq, const float* __restrict__ in_sum,
               const float* __restrict__ in_sq, const float* __restrict__ in_g,
               const float* __restrict__ in_b)
{
    const int HS = CIN + 8;                 // LDS stride per position (bf16 units)
    __shared__ u16 xs[160 * HS];            // [dz 0..3][hz 0..3][wz 0..9][c]
    __shared__ float scin[BNIN ? CIN : 1], shin[BNIN ? CIN : 1];

    int tid = threadIdx.x;
    int fid = blockIdx.x;                   // [0,784) = 8 XCDs x 98
    int g = (fid & 7) * 98 + (fid >> 3);
    int b = g / 196;
    int rem = g - b * 196;
    int d0 = (rem / 14) * 2, h0 = (rem % 14) * 2;

    if (BNIN) {
        if (tid < CIN) {
            float m = in_sum[tid] * (1.f / NSP);
            float v = in_sq[tid] * (1.f / NSP) - m * m;
            float sc = in_g[tid] * rsqrtf(v + EPS);
            scin[tid] = sc;
            shin[tid] = in_b[tid] - m * sc;
        }
        __syncthreads();
    }

    const int NCH = CIN / 8;
    for (int idx = tid; idx < 160 * NCH; idx += 256) {
        int pos = idx / NCH, ch = idx - pos * NCH;
        int dz = pos / 40, r2 = pos - dz * 40;
        int hz = r2 / 10, wz = r2 - hz * 10;
        int dd = d0 + dz - 1, hh = h0 + hz - 1, ww = wz - 1;
        uint4 val = make_uint4(0, 0, 0, 0);
        if ((unsigned)dd < 28u && (unsigned)hh < 28u && (unsigned)ww < 8u) {
            val = *(const uint4*)(X + ((size_t)(b * SP + dd * 224 + hh * 8 + ww) * CIN + ch * 8));
            if (BNIN) {
                int cb = ch * 8;
                float f0 = b2f_lo(val.x) * scin[cb]     + shin[cb];
                float f1 = b2f_hi(val.x) * scin[cb + 1] + shin[cb + 1];
                float f2 = b2f_lo(val.y) * scin[cb + 2] + shin[cb + 2];
                float f3 = b2f_hi(val.y) * scin[cb + 3] + shin[cb + 3];
                float f4 = b2f_lo(val.z) * scin[cb + 4] + shin[cb + 4];
                float f5 = b2f_hi(val.z) * scin[cb + 5] + shin[cb + 5];
                float f6 = b2f_lo(val.w) * scin[cb + 6] + shin[cb + 6];
                float f7 = b2f_hi(val.w) * scin[cb + 7] + shin[cb + 7];
                val.x = (unsigned)f2b(f0) | ((unsigned)f2b(f1) << 16);
                val.y = (unsigned)f2b(f2) | ((unsigned)f2b(f3) << 16);
                val.z = (unsigned)f2b(f4) | ((unsigned)f2b(f5) << 16);
                val.w = (unsigned)f2b(f6) | ((unsigned)f2b(f7) << 16);
            }
        }
        *(uint4*)(xs + pos * HS + ch * 8) = val;
    }
    __syncthreads();

    int l = tid & 63, wv = tid >> 6;
    int q = l >> 4, r = l & 15;
    int hl = r >> 3, wl = r & 7;
    int o_base = blockIdx.y * 64 + wv * 16;
    int o = o_base + r;

    const u16* a0p = xs + ((4 + hl + 1) * 10 + wl + 1) * HS + 8 * q;  // dl=0
    const u16* a1p = a0p + 40 * HS;                                   // dl=1
    const u16* wp0 = Wpk + (size_t)o * CIN + 8 * q;

    v4f acc0 = {0.f, 0.f, 0.f, 0.f}, acc1 = {0.f, 0.f, 0.f, 0.f};
    #pragma unroll
    for (int t = 0; t < 27; t++) {
        const int koff = ((t / 9) - 1) * 40 + (((t / 3) % 3) - 1) * 10 + (t % 3) - 1;
        const u16* wt = wp0 + (size_t)t * OPAD * CIN;
        #pragma unroll
        for (int c0 = 0; c0 < CIN; c0 += 32) {
            v8s a0 = *(const v8s*)(a0p + koff * HS + c0);
            v8s a1 = *(const v8s*)(a1p + koff * HS + c0);
            v8s bf = *(const v8s*)(wt + c0);
            acc0 = __builtin_amdgcn_mfma_f32_16x16x32_bf16(a0, bf, acc0, 0, 0, 0);
            acc1 = __builtin_amdgcn_mfma_f32_16x16x32_bf16(a1, bf, acc1, 0, 0, 0);
        }
    }

    if (OFFOUT) {
        float bo = (o < 81) ? bias[o] : 0.f;
        #pragma unroll
        for (int s2 = 0; s2 < 2; s2++) {
            v4f A = s2 ? acc1 : acc0;
            #pragma unroll
            for (int rg = 0; rg < 4; rg++) {
                int rowl = q * 4 + rg;
                int sp = (d0 + s2) * 224 + (h0 + (rowl >> 3)) * 8 + (rowl & 7);
                if (o < 81) offs[((size_t)(b * 81 + o)) * SP + sp] = A[rg] + bo;
            }
        }
    } else {
        float bo = bias[o];
        float rs = 0.f, rq = 0.f;
        #pragma unroll
        for (int s2 = 0; s2 < 2; s2++) {
            v4f A = s2 ? acc1 : acc0;
            #pragma unroll
            for (int rg = 0; rg < 4; rg++) {
                int rowl = q * 4 + rg;
                int sp = (d0 + s2) * 224 + (h0 + (rowl >> 3)) * 8 + (rowl & 7);
                float v = fmaxf(A[rg] + bo, 0.f);
                Ybf[(size_t)(b * SP + sp) * OPAD + o] = f2b(v);
                rs += v; rq += v * v;
            }
        }
        rs += __shfl_xor(rs, 16, 64); rs += __shfl_xor(rs, 32, 64);
        rq += __shfl_xor(rq, 16, 64); rq += __shfl_xor(rq, 32, 64);
        if (l < 16) { atomicAdd(&s_sum[o_base + l], rs); atomicAdd(&s_sq[o_base + l], rq); }
    }
}

// ---------------- BN apply on channel-minor bf16 (x3 has 2 consumers) ----------------
template<int C>
__global__ __launch_bounds__(256) void bn_bf(const u16* __restrict__ Y,
        const float* __restrict__ s_sum, const float* __restrict__ s_sq,
        const float* __restrict__ g, const float* __restrict__ bb,
        u16* __restrict__ Xo)
{
    int idx = blockIdx.x * 256 + threadIdx.x;   // [0, NSP*C)
    int c = idx & (C - 1);
    float m  = s_sum[c] * (1.f / NSP);
    float v  = s_sq[c] * (1.f / NSP) - m * m;
    float sc = g[c] * rsqrtf(v + EPS);
    Xo[idx] = f2b((b2f(Y[idx]) - m) * sc + bb[c]);
}

// ---------------- deformable conv (MFMA) -- R12 structure (measured local optimum) ----
// 32 pos / 256 thr / grid 800; 3 barriers per n; OFF staged to LDS once.
// R11 (reg prefetch), R13 (16-pos), R14 (all-n geom + dbuf), R15 (fused BN)
// all regressed vs this: 124 us, VGPR 52, LDS 22.5 KB, conflicts 2.7M.
__global__ __launch_bounds__(256) __attribute__((amdgpu_waves_per_eu(1, 4)))
void deform_pool(const u16* __restrict__ Ht, const float* __restrict__ OFF,
                 const u16* __restrict__ Wa, const float* __restrict__ db,
                 float* __restrict__ pooledraw, float* __restrict__ sumsq4)
{
    __shared__ float offs_lds[81 * 32];     // [ch][p]
    __shared__ int ig_s[32][8][2];          // [p][corner][{idx, g bits}]
    __shared__ u16 Vb[32][136];             // B operand [p][c] bf16, row pad +8
    __shared__ float reds[128], redq[128];

    int fid = blockIdx.x;          // [0,800)
    int xcd = fid & 7;
    int local = fid >> 3;          // [0,100)
    if (local >= 98) return;
    int b = xcd >> 1;
    int d = (xcd & 1) * 14 + local / 7;
    int h0 = (local % 7) * 4;

    int t = threadIdx.x;
    if (t < 128) { reds[t] = 0.f; redq[t] = 0.f; }

    int gp = t >> 3, gcr = t & 7;                  // geometry role
    int glh = gp >> 3, gw = gp & 7, gh = h0 + glh;
    int co = t & 15, pg = t >> 4;                  // phase2 role: c-oct, p-pair
    int l = t & 63, wv = t >> 6;                   // phase3 role
    int q = l >> 4, r = l & 15;

    v4f acc[2][2];                                 // [o-tile][p-tile]
    acc[0][0] = (v4f){0.f,0.f,0.f,0.f}; acc[0][1] = (v4f){0.f,0.f,0.f,0.f};
    acc[1][0] = (v4f){0.f,0.f,0.f,0.f}; acc[1][1] = (v4f){0.f,0.f,0.f,0.f};

    const u16* hb = Ht + (size_t)b * SP * 128;

    // ---- stage offsets for this block's 32 positions (coalesced, once) ----
    for (int i = t; i < 2592; i += 256) {
        int ch = i >> 5, p = i & 31;
        offs_lds[i] = OFF[(size_t)b * 81 * SP + (size_t)ch * SP
                          + d * 224 + (h0 + (p >> 3)) * 8 + (p & 7)];
    }

    for (int n = 0; n < 27; n++) {
        __syncthreads();   // prev phase3 done reading Vb (and offs_lds ready, n=0)
        {   // ---- geometry for (n, gp, gcr) ----
            int kd = n / 9 - 1, kh = (n / 3) % 3 - 1, kw = n % 3 - 1;
            float od  = offs_lds[n * 32 + gp];
            float oh  = offs_lds[(27 + n) * 32 + gp];
            float owv = offs_lds[(54 + n) * 32 + gp];
            float pd = fminf(fmaxf((float)(d + 1 + kd) + od, 0.f), 29.f);
            float ph = fminf(fmaxf((float)(gh + 1 + kh) + oh, 0.f), 29.f);
            float pw = fminf(fmaxf((float)(gw + 1 + kw) + owv, 0.f), 9.f);
            float qd = fminf(floorf(pd), 28.f);
            float qh = fminf(floorf(ph), 28.f);
            float qw = fminf(floorf(pw), 8.f);
            float td = fminf(pd - qd, 1.f);
            float th = fminf(ph - qh, 1.f);
            float tw = fminf(pw - qw, 1.f);
            int iqd = (int)qd - 1, iqh = (int)qh - 1, iqw = (int)qw - 1;
            int i = gcr >> 2, j = (gcr >> 1) & 1, k = gcr & 1;
            int du = iqd + i, hu = iqh + j, wu = iqw + k;
            bool val = (unsigned)du < 28u && (unsigned)hu < 28u && (unsigned)wu < 8u;
            float gg = (i ? td : 1.f - td) * (j ? th : 1.f - th) * (k ? tw : 1.f - tw);
            ig_s[gp][gcr][0] = val ? (du * 224 + hu * 8 + wu) : 0;
            ig_s[gp][gcr][1] = __float_as_int(val ? gg : 0.f);
        }
        __syncthreads();
        // ---- phase 2: V[p][c] trilinear sample, 8 channels/load ----
        #pragma unroll
        for (int pp = 0; pp < 2; pp++) {
            int p = pg * 2 + pp;
            float va[8] = {0.f,0.f,0.f,0.f,0.f,0.f,0.f,0.f};
            #pragma unroll
            for (int cr = 0; cr < 8; cr++) {
                int2 pr = *(const int2*)&ig_s[p][cr][0];
                float gg = __int_as_float(pr.y);
                uint4 xv = *(const uint4*)(hb + (size_t)pr.x * 128 + co * 8);
                va[0] = fmaf(gg, b2f_lo(xv.x), va[0]);
                va[1] = fmaf(gg, b2f_hi(xv.x), va[1]);
                va[2] = fmaf(gg, b2f_lo(xv.y), va[2]);
                va[3] = fmaf(gg, b2f_hi(xv.y), va[3]);
                va[4] = fmaf(gg, b2f_lo(xv.z), va[4]);
                va[5] = fmaf(gg, b2f_hi(xv.z), va[5]);
                va[6] = fmaf(gg, b2f_lo(xv.w), va[6]);
                va[7] = fmaf(gg, b2f_hi(xv.w), va[7]);
            }
            uint4 pk;
            pk.x = (unsigned)f2b(va[0]) | ((unsigned)f2b(va[1]) << 16);
            pk.y = (unsigned)f2b(va[2]) | ((unsigned)f2b(va[3]) << 16);
            pk.z = (unsigned)f2b(va[4]) | ((unsigned)f2b(va[5]) << 16);
            pk.w = (unsigned)f2b(va[6]) | ((unsigned)f2b(va[7]) << 16);
            *(uint4*)&Vb[p][co * 8] = pk;
        }
        __syncthreads();
        // ---- phase 3: out[o][p] += W[o][c] * V[c][p] via MFMA ----
        const u16* wn = Wa + (size_t)n * 16384;
        #pragma unroll
        for (int oti = 0; oti < 2; oti++) {
            int ot = wv * 2 + oti;
            #pragma unroll
            for (int kc = 0; kc < 4; kc++) {
                v8s af = *(const v8s*)(wn + ((((ot * 4 + kc) * 4 + q) * 16 + r) * 8));
                v8s bf0 = *(const v8s*)&Vb[r][kc * 32 + q * 8];
                v8s bf1 = *(const v8s*)&Vb[16 + r][kc * 32 + q * 8];
                acc[oti][0] = __builtin_amdgcn_mfma_f32_16x16x32_bf16(af, bf0, acc[oti][0], 0, 0, 0);
                acc[oti][1] = __builtin_amdgcn_mfma_f32_16x16x32_bf16(af, bf1, acc[oti][1], 0, 0, 0);
            }
        }
    }

    // ---- epilogue: bias + relu + pooled sum / sumsq ----
    #pragma unroll
    for (int oti = 0; oti < 2; oti++) {
        #pragma unroll
        for (int rg = 0; rg < 4; rg++) {
            int o = (wv * 2 + oti) * 16 + q * 4 + rg;
            float bo = db[o];
            float v0 = fmaxf(acc[oti][0][rg] + bo, 0.f);
            float v1 = fmaxf(acc[oti][1][rg] + bo, 0.f);
            float s = v0 + v1, qq = v0 * v0 + v1 * v1;
            s += __shfl_xor(s, 1, 64);  qq += __shfl_xor(qq, 1, 64);
            s += __shfl_xor(s, 2, 64);  qq += __shfl_xor(qq, 2, 64);
            s += __shfl_xor(s, 4, 64);  qq += __shfl_xor(qq, 4, 64);
            s += __shfl_xor(s, 8, 64);  qq += __shfl_xor(qq, 8, 64);
            if (r == 0) { atomicAdd(&reds[o], s); atomicAdd(&redq[o], qq); }
        }
    }
    __syncthreads();
    if (t < 128) {
        atomicAdd(&pooledraw[b * 128 + t], reds[t]);
        atomicAdd(&sumsq4[t], redq[t]);
    }
}

// ---------------- tail kernel: block 0 = BN4+pool+FC+log_softmax; rest publish offsets ----
__global__ __launch_bounds__(256) void final_head_emit(const float* __restrict__ pooledraw,
        const float* __restrict__ sumsq4, const float* __restrict__ g4,
        const float* __restrict__ b4, const float* __restrict__ fcw,
        const float* __restrict__ fcb, const float* __restrict__ offw,
        float* __restrict__ out)
{
    int t = threadIdx.x;
    if (blockIdx.x > 0) {   // offsets copy: 1985 blocks x 256 x float4
        int idx = (blockIdx.x - 1) * 256 + t;
        if (idx < 508032) {
            float4 v = ((const float4*)offw)[idx];
            ((float4*)(out + 40))[idx] = v;
        }
        return;
    }
    __shared__ float pooled_s[4][128];
    __shared__ float logits[4][10];
    if (t < 128) {
        float s0 = pooledraw[t], s1 = pooledraw[128 + t];
        float s2 = pooledraw[256 + t], s3 = pooledraw[384 + t];
        float tot = s0 + s1 + s2 + s3;
        float m  = tot * (1.f / NSP);
        float v  = sumsq4[t] * (1.f / NSP) - m * m;
        float sc = g4[t] * rsqrtf(v + EPS);
        float sh = b4[t] - m * sc;
        pooled_s[0][t] = s0 * (1.f / SP) * sc + sh;
        pooled_s[1][t] = s1 * (1.f / SP) * sc + sh;
        pooled_s[2][t] = s2 * (1.f / SP) * sc + sh;
        pooled_s[3][t] = s3 * (1.f / SP) * sc + sh;
    }
    __syncthreads();
    if (t < 40) {
        int b = t / 10, j = t % 10;
        float l = fcb[j];
        for (int c = 0; c < 128; c++) l = fmaf(pooled_s[b][c], fcw[j * 128 + c], l);
        logits[b][j] = l;
    }
    __syncthreads();
    if (t < 4) {
        float mx = -1e30f;
        for (int j = 0; j < 10; j++) mx = fmaxf(mx, logits[t][j]);
        float se = 0.f;
        for (int j = 0; j < 10; j++) se += expf(logits[t][j] - mx);
        float lse = mx + logf(se);
        for (int j = 0; j < 10; j++) out[t * 10 + j] = logits[t][j] - lse;
    }
}

extern "C" void kernel_launch(void* const* d_in, const int* in_sizes, int n_in,
                              void* d_out, int out_size, void* d_ws, size_t ws_size,
                              hipStream_t stream)
{
    (void)in_sizes; (void)n_in; (void)out_size; (void)ws_size;
    const float* x   = (const float*)d_in[0];
    const float* c1w = (const float*)d_in[1];
    const float* c1b = (const float*)d_in[2];
    const float* g1  = (const float*)d_in[3];
    const float* b1  = (const float*)d_in[4];
    const float* c2w = (const float*)d_in[5];
    const float* c2b = (const float*)d_in[6];
    const float* g2  = (const float*)d_in[7];
    const float* b2  = (const float*)d_in[8];
    const float* c3w = (const float*)d_in[9];
    const float* c3b = (const float*)d_in[10];
    const float* g3  = (const float*)d_in[11];
    const float* b3  = (const float*)d_in[12];
    const float* ow  = (const float*)d_in[13];
    const float* ob  = (const float*)d_in[14];
    const float* dw  = (const float*)d_in[15];
    const float* db  = (const float*)d_in[16];
    const float* g4  = (const float*)d_in[17];
    const float* b4  = (const float*)d_in[18];
    const float* fcw = (const float*)d_in[19];
    const float* fcb = (const float*)d_in[20];

    float* ws = (float*)d_ws;
    float* S1 = ws + 0,   *Q1 = ws + 32;
    float* S2 = ws + 64,  *Q2 = ws + 128;
    float* S3 = ws + 192, *Q3 = ws + 320;
    float* PO = ws + 448;   // 4*128
    float* Q4 = ws + 960;   // 128
    u16* y1bf = (u16*)(ws + 2048);         // NSP*32
    u16* y2bf = y1bf + 802816;             // NSP*64
    u16* y3bf = y2bf + 1605632;            // NSP*128
    u16* x3bf = y3bf + 3211264;
    u16* wpk2 = x3bf + 3211264;            // 27*64*32
    u16* wpk3 = wpk2 + 55296;              // 27*128*64
    u16* wpko = wpk3 + 221184;             // 27*128*128 (o>=81 zero)
    u16* dwa  = wpko + 442368;             // 27*128*128 A-frag layout bf16
    float* offw = (float*)(dwa + 442368);  // 4*81*SP fp32 (ws copy of offsets)

    float* outf = (float*)d_out;

    hipMemsetAsync(ws, 0, 2048 * sizeof(float), stream);
    prepack_all<<<4536, 256, 0, stream>>>(c2w, c3w, ow, dw, wpk2, wpk3, wpko, dwa);

    conv1_shfl<<<dim3(104, 2), 256, 0, stream>>>(x, c1w, c1b, y1bf);
    stats32<<<98, 256, 0, stream>>>(y1bf, S1, Q1);

    conv_mfma<32, 64, false, true><<<dim3(784, 1), 256, 0, stream>>>(
        y1bf, wpk2, c2b, y2bf, nullptr, S2, Q2, S1, Q1, g1, b1);

    conv_mfma<64, 128, false, true><<<dim3(784, 2), 256, 0, stream>>>(
        y2bf, wpk3, c3b, y3bf, nullptr, S3, Q3, S2, Q2, g2, b2);

    bn_bf<128><<<12544, 256, 0, stream>>>(y3bf, S3, Q3, g3, b3, x3bf);

    // offsets computed into WORKSPACE; d_out is written only at the tail
    conv_mfma<128, 128, true, false><<<dim3(784, 2), 256, 0, stream>>>(
        x3bf, wpko, ob, nullptr, offw, nullptr, nullptr, nullptr, nullptr, nullptr, nullptr);
    deform_pool<<<800, 256, 0, stream>>>(x3bf, offw, dwa, db, PO, Q4);
    final_head_emit<<<1986, 256, 0, stream>>>(PO, Q4, g4, b4, fcw, fcb, offw, outf);
}